// Round 2
// baseline (1685.641 us; speedup 1.0000x reference)
//
#include <hip/hip_runtime.h>

#define NB 4096          // number of boxes
#define NWRD 64          // 64-bit words per bitmask row (NB/64)
#define LLOC 16384       // number of locations
#define IOU_THR 0.5f

typedef unsigned long long u64;

// ---------------- Part 2: pred boxes + centerness (elementwise) --------------
__global__ void pred_kernel(const float* __restrict__ loc,
                            const float* __restrict__ deltas,
                            const int* __restrict__ stride_p,
                            float* __restrict__ out) {
    int i = blockIdx.x * blockDim.x + threadIdx.x;
    if (i >= LLOC) return;
    float s = (float)stride_p[0];
    float2 p = ((const float2*)loc)[i];
    float4 d = ((const float4*)deltas)[i];
    float c0 = fmaxf(d.x, 0.f), c1 = fmaxf(d.y, 0.f);
    float c2 = fmaxf(d.z, 0.f), c3 = fmaxf(d.w, 0.f);
    float b0 = p.x - c0 * s;
    float b1 = p.y - c1 * s;
    float b2 = p.x + c2 * s;
    float b3 = p.y + c3 * s;
    float lr_min = fminf(d.x, d.z), tb_min = fminf(d.y, d.w);
    float lr_max = fmaxf(d.x, d.z), tb_max = fmaxf(d.y, d.w);
    float cent = sqrtf((lr_min * tb_min) / (lr_max * tb_max));
    if (d.x == -1.f && d.y == -1.f && d.z == -1.f && d.w == -1.f) cent = -1.f;
    float* o = out + (size_t)i * 5;
    o[0] = b0; o[1] = b1; o[2] = b2; o[3] = b3; o[4] = cent;
}

// ---------------- max over all box coordinates -------------------------------
__global__ void maxc_kernel(const float* __restrict__ boxes, float* __restrict__ maxc) {
    __shared__ float red[4];
    int t = threadIdx.x;  // 256 threads
    float m = -3.0e38f;
    for (int i = t; i < NB * 4; i += 256) m = fmaxf(m, boxes[i]);
    for (int o = 32; o > 0; o >>= 1) m = fmaxf(m, __shfl_down(m, o));
    if ((t & 63) == 0) red[t >> 6] = m;
    __syncthreads();
    if (t == 0) *maxc = fmaxf(fmaxf(red[0], red[1]), fmaxf(red[2], red[3]));
}

// ---------------- class-offset boxes + areas ---------------------------------
__global__ void prep_kernel(const float* __restrict__ boxes, const int* __restrict__ cls,
                            const float* __restrict__ maxc,
                            float* __restrict__ bnms, float* __restrict__ areas) {
    int i = blockIdx.x * 256 + threadIdx.x;
    if (i >= NB) return;
    float off = (float)cls[i] * (maxc[0] + 1.0f);
    float4 b = ((const float4*)boxes)[i];
    b.x += off; b.y += off; b.z += off; b.w += off;
    ((float4*)bnms)[i] = b;
    areas[i] = (b.z - b.x) * (b.w - b.y);
}

// ---------------- rank sort by score (desc, tie -> lower index) --------------
__global__ void rank_kernel(const float* __restrict__ scores, int* __restrict__ sidx) {
    __shared__ float s[NB];
    int t = threadIdx.x;  // 256
    for (int i = t; i < NB; i += 256) s[i] = scores[i];
    __syncthreads();
    int i = blockIdx.x * 256 + t;
    float my = s[i];
    int rank = 0;
#pragma unroll 4
    for (int j = 0; j < NB; ++j) {
        float sj = s[j];
        rank += (sj > my) || (sj == my && j < i);
    }
    sidx[rank] = i;
}

// ---------------- gather boxes/areas into sorted order -----------------------
__global__ void gather_kernel(const float* __restrict__ bnms, const float* __restrict__ areas,
                              const int* __restrict__ sidx,
                              float* __restrict__ sboxes, float* __restrict__ sareas) {
    int i = blockIdx.x * 256 + threadIdx.x;
    if (i >= NB) return;
    int j = sidx[i];
    ((float4*)sboxes)[i] = ((const float4*)bnms)[j];
    sareas[i] = areas[j];
}

// ---------------- pairwise IoU > thr bitmask (64x64 tiles) -------------------
__global__ void mask_kernel(const float* __restrict__ sboxes, const float* __restrict__ sareas,
                            u64* __restrict__ mask) {
    __shared__ float4 cb[64];
    __shared__ float ca[64];
    int t = threadIdx.x;            // 64 threads = one wave
    int c = blockIdx.x, r = blockIdx.y;
    cb[t] = ((const float4*)sboxes)[c * 64 + t];
    ca[t] = sareas[c * 64 + t];
    __syncthreads();
    float4 rb = ((const float4*)sboxes)[r * 64 + t];
    float ra = sareas[r * 64 + t];
    u64 w = 0;
#pragma unroll 8
    for (int j = 0; j < 64; ++j) {
        float4 b = cb[j];
        float xi = fminf(rb.z, b.z) - fmaxf(rb.x, b.x);
        float yi = fminf(rb.w, b.w) - fmaxf(rb.y, b.y);
        float inter = fmaxf(xi, 0.f) * fmaxf(yi, 0.f);
        float iou = inter / (ra + ca[j] - inter);
        w |= (u64)(iou > IOU_THR) << j;
    }
    mask[(u64)(r * 64 + t) * NWRD + c] = w;
}

// ---------------- serial greedy scan (1 wave, register-prefetched) -----------
__device__ inline u64 shfl_u64(u64 v, int lane) {
    int lo = __shfl((int)(unsigned)(v & 0xffffffffull), lane);
    int hi = __shfl((int)(unsigned)(v >> 32), lane);
    return ((u64)(unsigned)hi << 32) | (unsigned)lo;
}

__global__ void scan_kernel(const u64* __restrict__ mask, const int* __restrict__ sidx,
                            float* __restrict__ keep_out) {
    int lane = threadIdx.x;  // 64 threads, 1 wave
    u64 acc = 0;             // lane w holds removed-word w (boxes 64w..64w+63)
    u64 rows[64];            // word `lane` of each of the 64 rows of current block panel

    // prologue: prefetch block 0's row panel + colw for blocks 0 and 1
#pragma unroll
    for (int j = 0; j < 64; ++j) rows[j] = mask[(u64)j * NWRD + lane];
    u64 colw_cur  = mask[(u64)lane * NWRD + 0];
    u64 colw_next = mask[(u64)(64 + lane) * NWRD + 1];

    for (int b = 0; b < 64; ++b) {
        u64 gw = shfl_u64(acc, b);
        bool removed = (gw >> lane) & 1ull;
        u64 decided = 0, keptm = 0;
        while (true) {
            u64 remb = __ballot(removed);
            u64 avail = ~(decided | remb);
            if (avail == 0ull) break;
            int i = __builtin_ctzll(avail);
            decided |= 1ull << i;
            keptm |= 1ull << i;
            removed = removed || ((colw_cur >> i) & 1ull);
        }
        keep_out[sidx[b * 64 + lane]] = ((keptm >> lane) & 1ull) ? 1.0f : 0.0f;

        // merge kept rows (pure VALU/SALU — keptm is wave-uniform)
#pragma unroll
        for (int j = 0; j < 64; ++j)
            if ((keptm >> j) & 1ull) acc |= rows[j];

        // prefetch next block's panel; colw stays two blocks ahead
        if (b < 63) {
            colw_cur = colw_next;
#pragma unroll
            for (int j = 0; j < 64; ++j)
                rows[j] = mask[(u64)((b + 1) * 64 + j) * NWRD + lane];
            if (b < 62)
                colw_next = mask[(u64)((b + 2) * 64 + lane) * NWRD + (b + 2)];
        }
    }
}

extern "C" void kernel_launch(void* const* d_in, const int* in_sizes, int n_in,
                              void* d_out, int out_size, void* d_ws, size_t ws_size,
                              hipStream_t stream) {
    const float* boxes   = (const float*)d_in[0];   // (4096,4)
    const float* scores  = (const float*)d_in[1];   // (4096,)
    const int*   cls     = (const int*)d_in[2];     // (4096,)
    const float* loc     = (const float*)d_in[3];   // (16384,2)
    const float* deltas  = (const float*)d_in[4];   // (16384,4)
    const int*   stride  = (const int*)d_in[5];     // scalar

    float* out = (float*)d_out;
    float* keep_out = out;          // 4096 floats (bool as 0/1)
    float* pred_out = out + NB;     // 16384*5 floats

    // workspace layout
    char* ws = (char*)d_ws;
    float* maxc   = (float*)ws;                      ws += 16;
    float* bnms   = (float*)ws;                      ws += NB * 4 * sizeof(float);
    float* areas  = (float*)ws;                      ws += NB * sizeof(float);
    int*   sidx   = (int*)ws;                        ws += NB * sizeof(int);
    float* sboxes = (float*)ws;                      ws += NB * 4 * sizeof(float);
    float* sareas = (float*)ws;                      ws += NB * sizeof(float);
    u64*   mask   = (u64*)ws;                        // NB * NWRD * 8 = 2 MiB

    pred_kernel<<<LLOC / 256, 256, 0, stream>>>(loc, deltas, stride, pred_out);
    maxc_kernel<<<1, 256, 0, stream>>>(boxes, maxc);
    prep_kernel<<<NB / 256, 256, 0, stream>>>(boxes, cls, maxc, bnms, areas);
    rank_kernel<<<NB / 256, 256, 0, stream>>>(scores, sidx);
    gather_kernel<<<NB / 256, 256, 0, stream>>>(bnms, areas, sidx, sboxes, sareas);
    mask_kernel<<<dim3(NWRD, NWRD), 64, 0, stream>>>(sboxes, sareas, mask);
    scan_kernel<<<1, 64, 0, stream>>>(mask, sidx, keep_out);
}

// Round 3
// 407.873 us; speedup vs baseline: 4.1328x; 4.1328x over previous
//
#include <hip/hip_runtime.h>
#include <stdint.h>

#define NB 4096          // number of boxes
#define NWRD 64          // 64-bit words per bitmask row (NB/64)
#define NBLK 64          // 64 blocks of 64 boxes
#define LLOC 16384       // number of locations
#define IOU_THR 0.5f

typedef unsigned long long u64;

__device__ __forceinline__ u64 readlane64(u64 v, int lane) {
    unsigned lo = (unsigned)__builtin_amdgcn_readlane((int)(unsigned)(v & 0xffffffffull), lane);
    unsigned hi = (unsigned)__builtin_amdgcn_readlane((int)(unsigned)(v >> 32), lane);
    return ((u64)hi << 32) | (u64)lo;
}

// ---------------- fused front: pred (blocks 0-63), rank (64-79), maxc (80) ---
__global__ void __launch_bounds__(256) fused_front(
        const float* __restrict__ boxes, const float* __restrict__ scores,
        const float* __restrict__ loc, const float* __restrict__ deltas,
        const int* __restrict__ stride_p,
        float* __restrict__ pred_out, float* __restrict__ maxc,
        int* __restrict__ sidx) {
    __shared__ float sh[NB];
    __shared__ float red[4];
    int blk = blockIdx.x;
    int t = threadIdx.x;

    if (blk < 64) {
        // ---- pred boxes + centerness ----
        int i = blk * 256 + t;
        float s = (float)stride_p[0];
        float2 p = ((const float2*)loc)[i];
        float4 d = ((const float4*)deltas)[i];
        float c0 = fmaxf(d.x, 0.f), c1 = fmaxf(d.y, 0.f);
        float c2 = fmaxf(d.z, 0.f), c3 = fmaxf(d.w, 0.f);
        float b0 = p.x - c0 * s;
        float b1 = p.y - c1 * s;
        float b2 = p.x + c2 * s;
        float b3 = p.y + c3 * s;
        float lr_min = fminf(d.x, d.z), tb_min = fminf(d.y, d.w);
        float lr_max = fmaxf(d.x, d.z), tb_max = fmaxf(d.y, d.w);
        float cent = sqrtf((lr_min * tb_min) / (lr_max * tb_max));
        if (d.x == -1.f && d.y == -1.f && d.z == -1.f && d.w == -1.f) cent = -1.f;
        float* o = pred_out + (size_t)i * 5;
        o[0] = b0; o[1] = b1; o[2] = b2; o[3] = b3; o[4] = cent;
    } else if (blk < 80) {
        // ---- rank sort by score (desc, tie -> lower index) ----
        for (int i = t; i < NB; i += 256) sh[i] = scores[i];
        __syncthreads();
        int i = (blk - 64) * 256 + t;
        float my = sh[i];
        int rank = 0;
#pragma unroll 8
        for (int j = 0; j < NB; ++j) {
            float sj = sh[j];
            rank += (sj > my) || (sj == my && j < i);
        }
        sidx[rank] = i;
    } else {
        // ---- max coordinate ----
        float m = -3.0e38f;
        for (int i = t; i < NB * 4; i += 256) m = fmaxf(m, boxes[i]);
        for (int o = 32; o > 0; o >>= 1) m = fmaxf(m, __shfl_down(m, o));
        if ((t & 63) == 0) red[t >> 6] = m;
        __syncthreads();
        if (t == 0) *maxc = fmaxf(fmaxf(red[0], red[1]), fmaxf(red[2], red[3]));
    }
}

// ---------------- fused prep+gather: sorted offset-boxes + areas -------------
__global__ void __launch_bounds__(256) prep_gather(
        const float* __restrict__ boxes, const int* __restrict__ cls,
        const float* __restrict__ maxc, const int* __restrict__ sidx,
        float* __restrict__ sboxes, float* __restrict__ sareas) {
    int i = blockIdx.x * 256 + threadIdx.x;
    if (i >= NB) return;
    int j = sidx[i];
    float off = (float)cls[j] * (maxc[0] + 1.0f);
    float4 b = ((const float4*)boxes)[j];
    b.x += off; b.y += off; b.z += off; b.w += off;
    ((float4*)sboxes)[i] = b;
    sareas[i] = (b.z - b.x) * (b.w - b.y);
}

// ---------------- pairwise IoU > thr bitmask (64x64 tiles) -------------------
__global__ void __launch_bounds__(64) mask_kernel(
        const float* __restrict__ sboxes, const float* __restrict__ sareas,
        u64* __restrict__ mask) {
    __shared__ float4 cb[64];
    __shared__ float ca[64];
    int t = threadIdx.x;            // 64 threads = one wave
    int c = blockIdx.x, r = blockIdx.y;
    cb[t] = ((const float4*)sboxes)[c * 64 + t];
    ca[t] = sareas[c * 64 + t];
    __syncthreads();
    float4 rb = ((const float4*)sboxes)[r * 64 + t];
    float ra = sareas[r * 64 + t];
    u64 w = 0;
#pragma unroll 8
    for (int j = 0; j < 64; ++j) {
        float4 b = cb[j];
        float xi = fminf(rb.z, b.z) - fmaxf(rb.x, b.x);
        float yi = fminf(rb.w, b.w) - fmaxf(rb.y, b.y);
        float inter = fmaxf(xi, 0.f) * fmaxf(yi, 0.f);
        float iou = inter / (ra + ca[j] - inter);
        w |= (u64)(iou > IOU_THR) << j;
    }
    mask[(u64)(r * 64 + t) * NWRD + c] = w;
}

// ---------------- serial greedy scan: LDS-staged panels + scalar decisions ---
__global__ void __launch_bounds__(64) scan_kernel(
        const u64* __restrict__ mask, const int* __restrict__ sidx,
        float* __restrict__ keep_out) {
    // 2 x 32 KiB double-buffered row panel (64 rows x 64 words) = 64 KiB LDS
    __shared__ u64 panel[2][NBLK * NWRD];
    const int lane = threadIdx.x;   // 64 threads, 1 wave

    // prologue: DMA panel 0 into buffer 0
    {
        const u64* gp = mask;       // panel b starts at mask + b*4096
#pragma unroll
        for (int c = 0; c < 32; ++c) {
            __builtin_amdgcn_global_load_lds(
                (const __attribute__((address_space(1))) void*)(gp + c * 128 + lane * 2),
                (__attribute__((address_space(3))) void*)(&panel[0][c * 128]),
                16, 0, 0);
        }
    }
    __syncthreads();

    u64 accv = 0;      // lane w holds removed-word w (OR of kept rows so far)
    u64 keptall = 0;   // lane b will hold keptm of block b

    for (int b = 0; b < NBLK; ++b) {
        const int buf = b & 1;

        // 1. issue DMA prefetch of panel b+1 into the other buffer
        if (b < NBLK - 1) {
            const u64* gp = mask + (u64)(b + 1) * (NBLK * NWRD);
#pragma unroll
            for (int c = 0; c < 32; ++c) {
                __builtin_amdgcn_global_load_lds(
                    (const __attribute__((address_space(1))) void*)(gp + c * 128 + lane * 2),
                    (__attribute__((address_space(3))) void*)(&panel[buf ^ 1][c * 128]),
                    16, 0, 0);
            }
        }

        // 2. decision for block b — pure scalar greedy over 64 boxes
        //    lane j's column word (mask symmetric => row j word b of this panel)
        u64 colw = panel[buf][lane * NWRD + b];
        u64 rem = readlane64(accv, b);        // removed-in mask for this block
        u64 avail = ~rem;
        u64 keptm = 0;
        while (avail) {
            int i = (int)__builtin_ctzll(avail);   // highest-score available
            keptm |= 1ull << i;
            u64 coli = readlane64(colw, i);        // boxes i suppresses (incl. i)
            avail &= ~coli;
        }
        if (lane == b) keptall = keptm;

        // 3. merge kept rows into accumulator (64 pipelined ds_read_b64)
        {
            const u64* pb = &panel[buf][0];
            u64 a = accv;
#pragma unroll
            for (int j = 0; j < 64; ++j) {
                u64 m = pb[j * NWRD + lane];
                u64 sel = ((keptm >> j) & 1ull) ? ~0ull : 0ull;
                a |= (m & sel);
            }
            accv = a;
        }

        // 4. barrier: drains panel b+1 DMA (issued ~1.5K cycles ago)
        __syncthreads();
    }

    // epilogue: write keep mask (pipelined, no per-iteration store drains)
    for (int bb = 0; bb < NBLK; ++bb) {
        u64 kw = readlane64(keptall, bb);
        int idx = sidx[bb * 64 + lane];            // coalesced load
        keep_out[idx] = ((kw >> lane) & 1ull) ? 1.0f : 0.0f;
    }
}

extern "C" void kernel_launch(void* const* d_in, const int* in_sizes, int n_in,
                              void* d_out, int out_size, void* d_ws, size_t ws_size,
                              hipStream_t stream) {
    const float* boxes   = (const float*)d_in[0];   // (4096,4)
    const float* scores  = (const float*)d_in[1];   // (4096,)
    const int*   cls     = (const int*)d_in[2];     // (4096,)
    const float* loc     = (const float*)d_in[3];   // (16384,2)
    const float* deltas  = (const float*)d_in[4];   // (16384,4)
    const int*   stride  = (const int*)d_in[5];     // scalar

    float* out = (float*)d_out;
    float* keep_out = out;          // 4096 floats (bool as 0/1)
    float* pred_out = out + NB;     // 16384*5 floats

    // workspace layout (16B-aligned pieces)
    char* ws = (char*)d_ws;
    float* maxc   = (float*)ws;                      ws += 16;
    int*   sidx   = (int*)ws;                        ws += NB * sizeof(int);
    float* sboxes = (float*)ws;                      ws += NB * 4 * sizeof(float);
    float* sareas = (float*)ws;                      ws += NB * sizeof(float);
    u64*   mask   = (u64*)ws;                        // NB * NWRD * 8 = 2 MiB

    fused_front<<<81, 256, 0, stream>>>(boxes, scores, loc, deltas, stride,
                                        pred_out, maxc, sidx);
    prep_gather<<<NB / 256, 256, 0, stream>>>(boxes, cls, maxc, sidx, sboxes, sareas);
    mask_kernel<<<dim3(NWRD, NWRD), 64, 0, stream>>>(sboxes, sareas, mask);
    scan_kernel<<<1, 64, 0, stream>>>(mask, sidx, keep_out);
}

// Round 4
// 202.011 us; speedup vs baseline: 8.3443x; 2.0191x over previous
//
#include <hip/hip_runtime.h>
#include <stdint.h>

#define NB 4096          // number of boxes
#define NBLK 64          // 64 blocks of 64 boxes
#define LLOC 16384       // number of locations
#define IOU_THR 0.5f
#define ECAP 1024        // entry capacity per source block bucket

typedef unsigned long long u64;

__device__ __forceinline__ u64 readlane64(u64 v, int lane) {
    unsigned lo = (unsigned)__builtin_amdgcn_readlane((int)(unsigned)(v & 0xffffffffull), lane);
    unsigned hi = (unsigned)__builtin_amdgcn_readlane((int)(unsigned)(v >> 32), lane);
    return ((u64)hi << 32) | (u64)lo;
}

// ---------------- fused front: pred (0-63), rank (64-79), maxc+zero (80) ----
__global__ void __launch_bounds__(256) fused_front(
        const float* __restrict__ boxes, const float* __restrict__ scores,
        const float* __restrict__ loc, const float* __restrict__ deltas,
        const int* __restrict__ stride_p,
        float* __restrict__ pred_out, float* __restrict__ maxc,
        int* __restrict__ sidx, int* __restrict__ counts) {
    __shared__ __align__(16) float sh[NB];
    __shared__ float red[4];
    int blk = blockIdx.x;
    int t = threadIdx.x;

    if (blk < 64) {
        // ---- pred boxes + centerness ----
        int i = blk * 256 + t;
        float s = (float)stride_p[0];
        float2 p = ((const float2*)loc)[i];
        float4 d = ((const float4*)deltas)[i];
        float c0 = fmaxf(d.x, 0.f), c1 = fmaxf(d.y, 0.f);
        float c2 = fmaxf(d.z, 0.f), c3 = fmaxf(d.w, 0.f);
        float b0 = p.x - c0 * s;
        float b1 = p.y - c1 * s;
        float b2 = p.x + c2 * s;
        float b3 = p.y + c3 * s;
        float lr_min = fminf(d.x, d.z), tb_min = fminf(d.y, d.w);
        float lr_max = fmaxf(d.x, d.z), tb_max = fmaxf(d.y, d.w);
        float cent = sqrtf((lr_min * tb_min) / (lr_max * tb_max));
        if (d.x == -1.f && d.y == -1.f && d.z == -1.f && d.w == -1.f) cent = -1.f;
        float* o = pred_out + (size_t)i * 5;
        o[0] = b0; o[1] = b1; o[2] = b2; o[3] = b3; o[4] = cent;
    } else if (blk < 80) {
        // ---- rank sort by score (desc, tie -> lower index), float4 reads ----
        for (int i = t; i < NB; i += 256) sh[i] = scores[i];
        __syncthreads();
        int i = (blk - 64) * 256 + t;
        float my = sh[i];
        int rank = 0;
        const float4* sh4 = (const float4*)sh;
#pragma unroll 4
        for (int j4 = 0; j4 < NB / 4; ++j4) {
            float4 v = sh4[j4];
            int j = j4 * 4;
            rank += (v.x > my) || (v.x == my && (j + 0) < i);
            rank += (v.y > my) || (v.y == my && (j + 1) < i);
            rank += (v.z > my) || (v.z == my && (j + 2) < i);
            rank += (v.w > my) || (v.w == my && (j + 3) < i);
        }
        sidx[rank] = i;
    } else {
        // ---- max coordinate + zero bucket counters ----
        if (t < NBLK) counts[t] = 0;
        float m = -3.0e38f;
        for (int i = t; i < NB * 4; i += 256) m = fmaxf(m, boxes[i]);
        for (int o = 32; o > 0; o >>= 1) m = fmaxf(m, __shfl_down(m, o));
        if ((t & 63) == 0) red[t >> 6] = m;
        __syncthreads();
        if (t == 0) *maxc = fmaxf(fmaxf(red[0], red[1]), fmaxf(red[2], red[3]));
    }
}

// ---------------- fused prep+gather: sorted offset-boxes + areas -------------
__global__ void __launch_bounds__(256) prep_gather(
        const float* __restrict__ boxes, const int* __restrict__ cls,
        const float* __restrict__ maxc, const int* __restrict__ sidx,
        float* __restrict__ sboxes, float* __restrict__ sareas) {
    int i = blockIdx.x * 256 + threadIdx.x;
    if (i >= NB) return;
    int j = sidx[i];
    float off = (float)cls[j] * (maxc[0] + 1.0f);
    float4 b = ((const float4*)boxes)[j];
    b.x += off; b.y += off; b.z += off; b.w += off;
    ((float4*)sboxes)[i] = b;
    sareas[i] = (b.z - b.x) * (b.w - b.y);
}

// ---------------- sparse suppression-edge extraction (upper triangle) --------
// Entry: .x = local_row | (word_col<<8), .z/.w = 64-bit word (lo/hi).
// Bucketed by source block r (row/64). Only nonzero off-diagonal words stored.
__global__ void __launch_bounds__(64) edge_kernel(
        const float* __restrict__ sboxes, const float* __restrict__ sareas,
        int* __restrict__ counts, uint4* __restrict__ entries) {
    int c = blockIdx.x, r = blockIdx.y;
    if (c < r) return;                  // block-uniform early out (symmetry)
    __shared__ float4 cb[64];
    __shared__ float ca[64];
    int t = threadIdx.x;                // 64 threads = one wave
    cb[t] = ((const float4*)sboxes)[c * 64 + t];
    ca[t] = sareas[c * 64 + t];
    __syncthreads();
    float4 rb = ((const float4*)sboxes)[r * 64 + t];
    float ra = sareas[r * 64 + t];
    u64 w = 0;
#pragma unroll 8
    for (int j = 0; j < 64; ++j) {
        float4 b = cb[j];
        float xi = fminf(rb.z, b.z) - fmaxf(rb.x, b.x);
        float yi = fminf(rb.w, b.w) - fmaxf(rb.y, b.y);
        float inter = fmaxf(xi, 0.f) * fmaxf(yi, 0.f);
        float iou = inter / (ra + ca[j] - inter);
        w |= (u64)(iou > IOU_THR) << j;
    }
    if (c == r) w &= ~(1ull << t);      // drop self-overlap bit
    if (w) {
        int idx = atomicAdd(&counts[r], 1);
        if (idx < ECAP)
            entries[r * ECAP + idx] =
                make_uint4((unsigned)(t | (c << 8)), 0u,
                           (unsigned)(w & 0xffffffffull), (unsigned)(w >> 32));
    }
}

// ---------------- serial greedy scan over sparse edges (1 wave) --------------
__global__ void __launch_bounds__(64) scan_kernel(
        const int* __restrict__ counts, const uint4* __restrict__ entries,
        const int* __restrict__ sidx, float* __restrict__ keep_out) {
    const int lane = threadIdx.x;       // 64 threads, 1 wave
    int cnt_l = counts[lane];           // lane b holds block b's entry count
    u64 accv = 0;                       // lane w = removed-word w (4096 bits in regs)
    u64 keptall = 0;                    // lane b = keptm of block b
    u64 self = 1ull << lane;

    uint4 cur = entries[lane];          // block 0's entries (lane e holds entry e)
    for (int b = 0; b < NBLK; ++b) {
        uint4 nxt;
        if (b < NBLK - 1) nxt = entries[(b + 1) * ECAP + lane];  // prefetch

        int cnt = __builtin_amdgcn_readlane(cnt_l, b);
        if (cnt > ECAP) cnt = ECAP;
        int cfast = cnt < 64 ? cnt : 64;

        // pass 1: build within-block column words from diagonal entries
        u64 colw = self;
        for (int e = 0; e < cfast; ++e) {
            unsigned meta = (unsigned)__builtin_amdgcn_readlane((int)cur.x, e);
            int l = meta & 255, c = meta >> 8;
            if (c == b) {
                unsigned lo = (unsigned)__builtin_amdgcn_readlane((int)cur.z, e);
                unsigned hi = (unsigned)__builtin_amdgcn_readlane((int)cur.w, e);
                if (lane == l) colw |= ((u64)hi << 32) | lo;
            }
        }
        for (int e = 64; e < cnt; ++e) {         // overflow path (rare)
            uint4 x = entries[b * ECAP + e];     // uniform address -> broadcast
            int l = x.x & 255, c = x.x >> 8;
            if (c == b && lane == l) colw |= ((u64)x.w << 32) | x.z;
        }

        // decision: optimistic ballot; serial greedy only over conflicted set
        u64 rem = readlane64(accv, b);
        u64 avail = ~rem;
        u64 edges = colw & avail & ~self;
        u64 involved = __ballot(edges != 0ull) & avail;
        u64 keptm = avail & ~involved;
        u64 sub = involved;
        while (sub) {
            int i = (int)__builtin_ctzll(sub);   // highest score first
            keptm |= 1ull << i;
            u64 ci = readlane64(colw, i);
            sub &= ~(ci | (1ull << i));
        }
        if (lane == b) keptall = keptm;

        // pass 2: merge kept rows' words into the removed accumulator
        for (int e = 0; e < cfast; ++e) {
            unsigned meta = (unsigned)__builtin_amdgcn_readlane((int)cur.x, e);
            unsigned lo   = (unsigned)__builtin_amdgcn_readlane((int)cur.z, e);
            unsigned hi   = (unsigned)__builtin_amdgcn_readlane((int)cur.w, e);
            int l = meta & 255, c = meta >> 8;
            if (((keptm >> l) & 1ull) && lane == c) accv |= ((u64)hi << 32) | lo;
        }
        for (int e = 64; e < cnt; ++e) {         // overflow path (rare)
            uint4 x = entries[b * ECAP + e];
            int l = x.x & 255, c = x.x >> 8;
            if (((keptm >> l) & 1ull) && lane == c) accv |= ((u64)x.w << 32) | x.z;
        }
        cur = nxt;
    }

    // epilogue: write keep mask via sorted-index scatter
#pragma unroll 8
    for (int bb = 0; bb < NBLK; ++bb) {
        u64 kw = readlane64(keptall, bb);
        int idx = sidx[bb * 64 + lane];          // coalesced load
        keep_out[idx] = ((kw >> lane) & 1ull) ? 1.0f : 0.0f;
    }
}

extern "C" void kernel_launch(void* const* d_in, const int* in_sizes, int n_in,
                              void* d_out, int out_size, void* d_ws, size_t ws_size,
                              hipStream_t stream) {
    const float* boxes   = (const float*)d_in[0];   // (4096,4)
    const float* scores  = (const float*)d_in[1];   // (4096,)
    const int*   cls     = (const int*)d_in[2];     // (4096,)
    const float* loc     = (const float*)d_in[3];   // (16384,2)
    const float* deltas  = (const float*)d_in[4];   // (16384,4)
    const int*   stride  = (const int*)d_in[5];     // scalar

    float* out = (float*)d_out;
    float* keep_out = out;          // 4096 floats (bool as 0/1)
    float* pred_out = out + NB;     // 16384*5 floats

    // workspace layout (16B-aligned pieces), ~1.1 MiB total
    char* ws = (char*)d_ws;
    float* maxc    = (float*)ws;                     ws += 16;
    int*   sidx    = (int*)ws;                       ws += NB * sizeof(int);
    float* sboxes  = (float*)ws;                     ws += NB * 4 * sizeof(float);
    float* sareas  = (float*)ws;                     ws += NB * sizeof(float);
    int*   counts  = (int*)ws;                       ws += NBLK * sizeof(int) + 16;
    uint4* entries = (uint4*)ws;                     // NBLK * ECAP * 16 B = 1 MiB

    fused_front<<<81, 256, 0, stream>>>(boxes, scores, loc, deltas, stride,
                                        pred_out, maxc, sidx, counts);
    prep_gather<<<NB / 256, 256, 0, stream>>>(boxes, cls, maxc, sidx, sboxes, sareas);
    edge_kernel<<<dim3(NBLK, NBLK), 64, 0, stream>>>(sboxes, sareas, counts, entries);
    scan_kernel<<<1, 64, 0, stream>>>(counts, entries, sidx, keep_out);
}

// Round 5
// 114.776 us; speedup vs baseline: 14.6864x; 1.7601x over previous
//
#include <hip/hip_runtime.h>
#include <stdint.h>

#define NB 4096          // number of boxes
#define NBLK 64          // 64 blocks of 64 boxes
#define LLOC 16384       // number of locations
#define IOU_THR 0.5f
#define ECAP 1024        // entry capacity per source block bucket
#define RANKB 256        // rank blocks (16 boxes each)

typedef unsigned long long u64;

__device__ __forceinline__ u64 readlane64(u64 v, int lane) {
    unsigned lo = (unsigned)__builtin_amdgcn_readlane((int)(unsigned)(v & 0xffffffffull), lane);
    unsigned hi = (unsigned)__builtin_amdgcn_readlane((int)(unsigned)(v >> 32), lane);
    return ((u64)hi << 32) | (u64)lo;
}

// ------- fused front: pred (0-63), rank (64-319, wave-per-box), maxc (320) ---
__global__ void __launch_bounds__(256) fused_front(
        const float* __restrict__ boxes, const float* __restrict__ scores,
        const float* __restrict__ loc, const float* __restrict__ deltas,
        const int* __restrict__ stride_p,
        float* __restrict__ pred_out, float* __restrict__ maxc,
        int* __restrict__ sidx, int* __restrict__ counts) {
    __shared__ __align__(16) float sh[NB];
    __shared__ float red[4];
    int blk = blockIdx.x;
    int t = threadIdx.x;

    if (blk < 64) {
        // ---- pred boxes + centerness ----
        int i = blk * 256 + t;
        float s = (float)stride_p[0];
        float2 p = ((const float2*)loc)[i];
        float4 d = ((const float4*)deltas)[i];
        float c0 = fmaxf(d.x, 0.f), c1 = fmaxf(d.y, 0.f);
        float c2 = fmaxf(d.z, 0.f), c3 = fmaxf(d.w, 0.f);
        float b0 = p.x - c0 * s;
        float b1 = p.y - c1 * s;
        float b2 = p.x + c2 * s;
        float b3 = p.y + c3 * s;
        float lr_min = fminf(d.x, d.z), tb_min = fminf(d.y, d.w);
        float lr_max = fmaxf(d.x, d.z), tb_max = fmaxf(d.y, d.w);
        float cent = sqrtf((lr_min * tb_min) / (lr_max * tb_max));
        if (d.x == -1.f && d.y == -1.f && d.z == -1.f && d.w == -1.f) cent = -1.f;
        float* o = pred_out + (size_t)i * 5;
        o[0] = b0; o[1] = b1; o[2] = b2; o[3] = b3; o[4] = cent;
    } else if (blk < 64 + RANKB) {
        // ---- rank: one wave per box, 4 boxes/wave, 64-iteration j-loop ----
        for (int i = t; i < NB; i += 256) sh[i] = scores[i];
        __syncthreads();
        int wave = t >> 6, lane = t & 63;
        int base = (blk - 64) * 16 + wave * 4;     // 4 consecutive boxes
        float my0 = sh[base + 0], my1 = sh[base + 1];
        float my2 = sh[base + 2], my3 = sh[base + 3];
        int c0 = 0, c1 = 0, c2 = 0, c3 = 0;
#pragma unroll 8
        for (int k = 0; k < 64; ++k) {
            int j = lane + k * 64;                 // 2-way LDS bank alias: free
            float sj = sh[j];
            c0 += (sj > my0) || (sj == my0 && j < base + 0);
            c1 += (sj > my1) || (sj == my1 && j < base + 1);
            c2 += (sj > my2) || (sj == my2 && j < base + 2);
            c3 += (sj > my3) || (sj == my3 && j < base + 3);
        }
        for (int o = 32; o > 0; o >>= 1) {
            c0 += __shfl_down(c0, o); c1 += __shfl_down(c1, o);
            c2 += __shfl_down(c2, o); c3 += __shfl_down(c3, o);
        }
        if (lane == 0) {
            sidx[c0] = base + 0; sidx[c1] = base + 1;
            sidx[c2] = base + 2; sidx[c3] = base + 3;
        }
    } else {
        // ---- max coordinate + zero bucket counters ----
        if (t < NBLK) counts[t] = 0;
        float m = -3.0e38f;
        for (int i = t; i < NB * 4; i += 256) m = fmaxf(m, boxes[i]);
        for (int o = 32; o > 0; o >>= 1) m = fmaxf(m, __shfl_down(m, o));
        if ((t & 63) == 0) red[t >> 6] = m;
        __syncthreads();
        if (t == 0) *maxc = fmaxf(fmaxf(red[0], red[1]), fmaxf(red[2], red[3]));
    }
}

// ---------------- fused prep+gather: sorted offset-boxes + areas -------------
__global__ void __launch_bounds__(256) prep_gather(
        const float* __restrict__ boxes, const int* __restrict__ cls,
        const float* __restrict__ maxc, const int* __restrict__ sidx,
        float* __restrict__ sboxes, float* __restrict__ sareas) {
    int i = blockIdx.x * 256 + threadIdx.x;
    if (i >= NB) return;
    int j = sidx[i];
    float off = (float)cls[j] * (maxc[0] + 1.0f);
    float4 b = ((const float4*)boxes)[j];
    b.x += off; b.y += off; b.z += off; b.w += off;
    ((float4*)sboxes)[i] = b;
    sareas[i] = (b.z - b.x) * (b.w - b.y);
}

// ---------------- sparse suppression-edge extraction (upper triangle) --------
// Entry: .x = local_row | (word_col<<8), .z/.w = 64-bit word (lo/hi).
// Bucketed by source block r (row/64). Only nonzero off-diagonal words stored.
__global__ void __launch_bounds__(64) edge_kernel(
        const float* __restrict__ sboxes, const float* __restrict__ sareas,
        int* __restrict__ counts, uint4* __restrict__ entries) {
    int c = blockIdx.x, r = blockIdx.y;
    if (c < r) return;                  // block-uniform early out (symmetry)
    __shared__ float4 cb[64];
    __shared__ float ca[64];
    int t = threadIdx.x;                // 64 threads = one wave
    cb[t] = ((const float4*)sboxes)[c * 64 + t];
    ca[t] = sareas[c * 64 + t];
    __syncthreads();
    float4 rb = ((const float4*)sboxes)[r * 64 + t];
    float ra = sareas[r * 64 + t];
    u64 w = 0;
#pragma unroll 8
    for (int j = 0; j < 64; ++j) {
        float4 b = cb[j];
        float xi = fminf(rb.z, b.z) - fmaxf(rb.x, b.x);
        float yi = fminf(rb.w, b.w) - fmaxf(rb.y, b.y);
        float inter = fmaxf(xi, 0.f) * fmaxf(yi, 0.f);
        float iou = inter / (ra + ca[j] - inter);
        w |= (u64)(iou > IOU_THR) << j;
    }
    if (c == r) w &= ~(1ull << t);      // drop self-overlap bit
    if (w) {
        int idx = atomicAdd(&counts[r], 1);
        if (idx < ECAP)
            entries[r * ECAP + idx] =
                make_uint4((unsigned)(t | (c << 8)), 0u,
                           (unsigned)(w & 0xffffffffull), (unsigned)(w >> 32));
    }
}

// ---------------- serial greedy scan over sparse edges (1 wave) --------------
__global__ void __launch_bounds__(64) scan_kernel(
        const int* __restrict__ counts, const uint4* __restrict__ entries,
        const int* __restrict__ sidx, float* __restrict__ keep_out) {
    const int lane = threadIdx.x;       // 64 threads, 1 wave
    int cnt_l = counts[lane];           // lane b holds block b's entry count
    u64 accv = 0;                       // lane w = removed-word w (4096 bits in regs)
    u64 keptall = 0;                    // lane b = keptm of block b
    u64 self = 1ull << lane;

    uint4 cur = entries[lane];          // block 0's entries (lane e holds entry e)
    for (int b = 0; b < NBLK; ++b) {
        uint4 nxt;
        if (b < NBLK - 1) nxt = entries[(b + 1) * ECAP + lane];  // prefetch

        int cnt = __builtin_amdgcn_readlane(cnt_l, b);
        if (cnt > ECAP) cnt = ECAP;
        int cfast = cnt < 64 ? cnt : 64;

        // pass 1: build within-block column words from diagonal entries
        u64 colw = self;
        for (int e = 0; e < cfast; ++e) {
            unsigned meta = (unsigned)__builtin_amdgcn_readlane((int)cur.x, e);
            int l = meta & 255, c = meta >> 8;
            if (c == b) {
                unsigned lo = (unsigned)__builtin_amdgcn_readlane((int)cur.z, e);
                unsigned hi = (unsigned)__builtin_amdgcn_readlane((int)cur.w, e);
                if (lane == l) colw |= ((u64)hi << 32) | lo;
            }
        }
        for (int e = 64; e < cnt; ++e) {         // overflow path (rare)
            uint4 x = entries[b * ECAP + e];     // uniform address -> broadcast
            int l = x.x & 255, c = x.x >> 8;
            if (c == b && lane == l) colw |= ((u64)x.w << 32) | x.z;
        }

        // decision: optimistic ballot; serial greedy only over conflicted set
        u64 rem = readlane64(accv, b);
        u64 avail = ~rem;
        u64 edges = colw & avail & ~self;
        u64 involved = __ballot(edges != 0ull) & avail;
        u64 keptm = avail & ~involved;
        u64 sub = involved;
        while (sub) {
            int i = (int)__builtin_ctzll(sub);   // highest score first
            keptm |= 1ull << i;
            u64 ci = readlane64(colw, i);
            sub &= ~(ci | (1ull << i));
        }
        if (lane == b) keptall = keptm;

        // pass 2: merge kept rows' words into the removed accumulator
        for (int e = 0; e < cfast; ++e) {
            unsigned meta = (unsigned)__builtin_amdgcn_readlane((int)cur.x, e);
            unsigned lo   = (unsigned)__builtin_amdgcn_readlane((int)cur.z, e);
            unsigned hi   = (unsigned)__builtin_amdgcn_readlane((int)cur.w, e);
            int l = meta & 255, c = meta >> 8;
            if (((keptm >> l) & 1ull) && lane == c) accv |= ((u64)hi << 32) | lo;
        }
        for (int e = 64; e < cnt; ++e) {         // overflow path (rare)
            uint4 x = entries[b * ECAP + e];
            int l = x.x & 255, c = x.x >> 8;
            if (((keptm >> l) & 1ull) && lane == c) accv |= ((u64)x.w << 32) | x.z;
        }
        cur = nxt;
    }

    // epilogue: write keep mask via sorted-index scatter
#pragma unroll 8
    for (int bb = 0; bb < NBLK; ++bb) {
        u64 kw = readlane64(keptall, bb);
        int idx = sidx[bb * 64 + lane];          // coalesced load
        keep_out[idx] = ((kw >> lane) & 1ull) ? 1.0f : 0.0f;
    }
}

extern "C" void kernel_launch(void* const* d_in, const int* in_sizes, int n_in,
                              void* d_out, int out_size, void* d_ws, size_t ws_size,
                              hipStream_t stream) {
    const float* boxes   = (const float*)d_in[0];   // (4096,4)
    const float* scores  = (const float*)d_in[1];   // (4096,)
    const int*   cls     = (const int*)d_in[2];     // (4096,)
    const float* loc     = (const float*)d_in[3];   // (16384,2)
    const float* deltas  = (const float*)d_in[4];   // (16384,4)
    const int*   stride  = (const int*)d_in[5];     // scalar

    float* out = (float*)d_out;
    float* keep_out = out;          // 4096 floats (bool as 0/1)
    float* pred_out = out + NB;     // 16384*5 floats

    // workspace layout (16B-aligned pieces), ~1.1 MiB total
    char* ws = (char*)d_ws;
    float* maxc    = (float*)ws;                     ws += 16;
    int*   sidx    = (int*)ws;                       ws += NB * sizeof(int);
    float* sboxes  = (float*)ws;                     ws += NB * 4 * sizeof(float);
    float* sareas  = (float*)ws;                     ws += NB * sizeof(float);
    int*   counts  = (int*)ws;                       ws += NBLK * sizeof(int) + 16;
    uint4* entries = (uint4*)ws;                     // NBLK * ECAP * 16 B = 1 MiB

    fused_front<<<64 + RANKB + 1, 256, 0, stream>>>(boxes, scores, loc, deltas, stride,
                                                    pred_out, maxc, sidx, counts);
    prep_gather<<<NB / 256, 256, 0, stream>>>(boxes, cls, maxc, sidx, sboxes, sareas);
    edge_kernel<<<dim3(NBLK, NBLK), 64, 0, stream>>>(sboxes, sareas, counts, entries);
    scan_kernel<<<1, 64, 0, stream>>>(counts, entries, sidx, keep_out);
}

// Round 6
// 103.837 us; speedup vs baseline: 16.2335x; 1.1053x over previous
//
#include <hip/hip_runtime.h>
#include <stdint.h>

#define NB 4096          // number of boxes
#define NBLK 64          // 64 blocks of 64 boxes
#define LLOC 16384       // number of locations
#define IOU_THR 0.5f
#define ECAP 1024        // entry capacity per source block bucket
#define RANKB 256        // rank blocks (16 boxes each)
#define NTRI (NBLK * (NBLK + 1) / 2)   // 2080 upper-triangle tiles

typedef unsigned long long u64;

__device__ __forceinline__ u64 readlane64(u64 v, int lane) {
    unsigned lo = (unsigned)__builtin_amdgcn_readlane((int)(unsigned)(v & 0xffffffffull), lane);
    unsigned hi = (unsigned)__builtin_amdgcn_readlane((int)(unsigned)(v >> 32), lane);
    return ((u64)hi << 32) | (u64)lo;
}

// ------- fused front: pred (0-63), rank (64-319, wave-per-box), maxc (320) ---
__global__ void __launch_bounds__(256) fused_front(
        const float* __restrict__ boxes, const float* __restrict__ scores,
        const float* __restrict__ loc, const float* __restrict__ deltas,
        const int* __restrict__ stride_p,
        float* __restrict__ pred_out, float* __restrict__ maxc,
        int* __restrict__ sidx, int* __restrict__ counts) {
    __shared__ __align__(16) float sh[NB];
    __shared__ float red[4];
    int blk = blockIdx.x;
    int t = threadIdx.x;

    if (blk < 64) {
        // ---- pred boxes + centerness ----
        int i = blk * 256 + t;
        float s = (float)stride_p[0];
        float2 p = ((const float2*)loc)[i];
        float4 d = ((const float4*)deltas)[i];
        float c0 = fmaxf(d.x, 0.f), c1 = fmaxf(d.y, 0.f);
        float c2 = fmaxf(d.z, 0.f), c3 = fmaxf(d.w, 0.f);
        float b0 = p.x - c0 * s;
        float b1 = p.y - c1 * s;
        float b2 = p.x + c2 * s;
        float b3 = p.y + c3 * s;
        float lr_min = fminf(d.x, d.z), tb_min = fminf(d.y, d.w);
        float lr_max = fmaxf(d.x, d.z), tb_max = fmaxf(d.y, d.w);
        float cent = sqrtf((lr_min * tb_min) / (lr_max * tb_max));
        if (d.x == -1.f && d.y == -1.f && d.z == -1.f && d.w == -1.f) cent = -1.f;
        float* o = pred_out + (size_t)i * 5;
        o[0] = b0; o[1] = b1; o[2] = b2; o[3] = b3; o[4] = cent;
    } else if (blk < 64 + RANKB) {
        // ---- rank: one wave per box, 4 boxes/wave, 64-iteration j-loop ----
        for (int i = t; i < NB; i += 256) sh[i] = scores[i];
        __syncthreads();
        int wave = t >> 6, lane = t & 63;
        int base = (blk - 64) * 16 + wave * 4;     // 4 consecutive boxes
        float my0 = sh[base + 0], my1 = sh[base + 1];
        float my2 = sh[base + 2], my3 = sh[base + 3];
        int c0 = 0, c1 = 0, c2 = 0, c3 = 0;
#pragma unroll 8
        for (int k = 0; k < 64; ++k) {
            int j = lane + k * 64;                 // 2-way LDS bank alias: free
            float sj = sh[j];
            c0 += (sj > my0) || (sj == my0 && j < base + 0);
            c1 += (sj > my1) || (sj == my1 && j < base + 1);
            c2 += (sj > my2) || (sj == my2 && j < base + 2);
            c3 += (sj > my3) || (sj == my3 && j < base + 3);
        }
        for (int o = 32; o > 0; o >>= 1) {
            c0 += __shfl_down(c0, o); c1 += __shfl_down(c1, o);
            c2 += __shfl_down(c2, o); c3 += __shfl_down(c3, o);
        }
        if (lane == 0) {
            sidx[c0] = base + 0; sidx[c1] = base + 1;
            sidx[c2] = base + 2; sidx[c3] = base + 3;
        }
    } else {
        // ---- max coordinate + zero bucket counters ----
        if (t < NBLK) counts[t] = 0;
        float m = -3.0e38f;
        for (int i = t; i < NB * 4; i += 256) m = fmaxf(m, boxes[i]);
        for (int o = 32; o > 0; o >>= 1) m = fmaxf(m, __shfl_down(m, o));
        if ((t & 63) == 0) red[t >> 6] = m;
        __syncthreads();
        if (t == 0) *maxc = fmaxf(fmaxf(red[0], red[1]), fmaxf(red[2], red[3]));
    }
}

// -------- sparse suppression-edge extraction, inline gather, triangular ------
// Entry: .x = local_row | (word_col<<8), .z/.w = 64-bit word (lo/hi).
// Bucketed by source block r. Only nonzero off-diagonal words stored.
__global__ void __launch_bounds__(64) edge_kernel(
        const float* __restrict__ boxes, const int* __restrict__ cls,
        const float* __restrict__ maxc, const int* __restrict__ sidx,
        int* __restrict__ counts, uint4* __restrict__ entries) {
    // decode upper-triangle tile (r <= c) from linear block id (uniform scalar)
    int idx = blockIdx.x, r = 0;
    while (idx >= NBLK - r) { idx -= NBLK - r; ++r; }
    int c = r + idx;

    __shared__ float4 cb[64];
    __shared__ float ca[64];
    int t = threadIdx.x;                // 64 threads = one wave
    float mc1 = maxc[0] + 1.0f;

    // gather row-tile box (sorted order) for this lane
    int jr = sidx[r * 64 + t];
    float offr = (float)cls[jr] * mc1;
    float4 rb = ((const float4*)boxes)[jr];
    rb.x += offr; rb.y += offr; rb.z += offr; rb.w += offr;
    float ra = (rb.z - rb.x) * (rb.w - rb.y);

    // column tile into LDS (reuse row tile when on the diagonal)
    if (c == r) {
        cb[t] = rb; ca[t] = ra;
    } else {
        int jc = sidx[c * 64 + t];
        float offc = (float)cls[jc] * mc1;
        float4 b = ((const float4*)boxes)[jc];
        b.x += offc; b.y += offc; b.z += offc; b.w += offc;
        cb[t] = b; ca[t] = (b.z - b.x) * (b.w - b.y);
    }
    __syncthreads();

    u64 w = 0;
#pragma unroll 8
    for (int j = 0; j < 64; ++j) {
        float4 b = cb[j];
        float xi = fminf(rb.z, b.z) - fmaxf(rb.x, b.x);
        float yi = fminf(rb.w, b.w) - fmaxf(rb.y, b.y);
        float inter = fmaxf(xi, 0.f) * fmaxf(yi, 0.f);
        float iou = inter / (ra + ca[j] - inter);
        w |= (u64)(iou > IOU_THR) << j;
    }
    if (c == r) w &= ~(1ull << t);      // drop self-overlap bit
    if (w) {
        int slot = atomicAdd(&counts[r], 1);
        if (slot < ECAP)
            entries[r * ECAP + slot] =
                make_uint4((unsigned)(t | (c << 8)), 0u,
                           (unsigned)(w & 0xffffffffull), (unsigned)(w >> 32));
    }
}

// ---------------- serial greedy scan over sparse edges (1 wave) --------------
__global__ void __launch_bounds__(64) scan_kernel(
        const int* __restrict__ counts, const uint4* __restrict__ entries,
        const int* __restrict__ sidx, float* __restrict__ keep_out) {
    const int lane = threadIdx.x;       // 64 threads, 1 wave
    int cnt_l = counts[lane];           // lane b holds block b's entry count
    u64 accv = 0;                       // lane w = removed-word w (4096 bits in regs)
    u64 keptall = 0;                    // lane b = keptm of block b
    u64 self = 1ull << lane;

    // depth-2 prefetch: covers cross-XCD L2-miss latency (~600-900 cyc)
    uint4 cur = entries[lane];
    uint4 n1  = entries[ECAP + lane];
    for (int b = 0; b < NBLK; ++b) {
        uint4 n2;
        if (b < NBLK - 2) n2 = entries[(u64)(b + 2) * ECAP + lane];

        int cnt = __builtin_amdgcn_readlane(cnt_l, b);
        if (cnt > ECAP) cnt = ECAP;
        int cfast = cnt < 64 ? cnt : 64;

        // pass 1: build within-block column words from diagonal entries
        u64 colw = self;
        for (int e = 0; e < cfast; ++e) {
            unsigned meta = (unsigned)__builtin_amdgcn_readlane((int)cur.x, e);
            int l = meta & 255, c = meta >> 8;
            if (c == b) {
                unsigned lo = (unsigned)__builtin_amdgcn_readlane((int)cur.z, e);
                unsigned hi = (unsigned)__builtin_amdgcn_readlane((int)cur.w, e);
                if (lane == l) colw |= ((u64)hi << 32) | lo;
            }
        }
        for (int e = 64; e < cnt; ++e) {         // overflow path (rare)
            uint4 x = entries[(u64)b * ECAP + e];
            int l = x.x & 255, c = x.x >> 8;
            if (c == b && lane == l) colw |= ((u64)x.w << 32) | x.z;
        }

        // decision: optimistic ballot; serial greedy only over conflicted set
        u64 rem = readlane64(accv, b);
        u64 avail = ~rem;
        u64 edges = colw & avail & ~self;
        u64 involved = __ballot(edges != 0ull) & avail;
        u64 keptm = avail & ~involved;
        u64 sub = involved;
        while (sub) {
            int i = (int)__builtin_ctzll(sub);   // highest score first
            keptm |= 1ull << i;
            u64 ci = readlane64(colw, i);
            sub &= ~(ci | (1ull << i));
        }
        if (lane == b) keptall = keptm;

        // pass 2: merge kept rows' words into the removed accumulator
        for (int e = 0; e < cfast; ++e) {
            unsigned meta = (unsigned)__builtin_amdgcn_readlane((int)cur.x, e);
            unsigned lo   = (unsigned)__builtin_amdgcn_readlane((int)cur.z, e);
            unsigned hi   = (unsigned)__builtin_amdgcn_readlane((int)cur.w, e);
            int l = meta & 255, c = meta >> 8;
            if (((keptm >> l) & 1ull) && lane == c) accv |= ((u64)hi << 32) | lo;
        }
        for (int e = 64; e < cnt; ++e) {         // overflow path (rare)
            uint4 x = entries[(u64)b * ECAP + e];
            int l = x.x & 255, c = x.x >> 8;
            if (((keptm >> l) & 1ull) && lane == c) accv |= ((u64)x.w << 32) | x.z;
        }
        cur = n1; n1 = n2;
    }

    // epilogue: write keep mask via sorted-index scatter
#pragma unroll 8
    for (int bb = 0; bb < NBLK; ++bb) {
        u64 kw = readlane64(keptall, bb);
        int idx = sidx[bb * 64 + lane];          // coalesced load
        keep_out[idx] = ((kw >> lane) & 1ull) ? 1.0f : 0.0f;
    }
}

extern "C" void kernel_launch(void* const* d_in, const int* in_sizes, int n_in,
                              void* d_out, int out_size, void* d_ws, size_t ws_size,
                              hipStream_t stream) {
    const float* boxes   = (const float*)d_in[0];   // (4096,4)
    const float* scores  = (const float*)d_in[1];   // (4096,)
    const int*   cls     = (const int*)d_in[2];     // (4096,)
    const float* loc     = (const float*)d_in[3];   // (16384,2)
    const float* deltas  = (const float*)d_in[4];   // (16384,4)
    const int*   stride  = (const int*)d_in[5];     // scalar

    float* out = (float*)d_out;
    float* keep_out = out;          // 4096 floats (bool as 0/1)
    float* pred_out = out + NB;     // 16384*5 floats

    // workspace layout (16B-aligned pieces), ~1.05 MiB total
    char* ws = (char*)d_ws;
    float* maxc    = (float*)ws;                     ws += 16;
    int*   sidx    = (int*)ws;                       ws += NB * sizeof(int);
    int*   counts  = (int*)ws;                       ws += NBLK * sizeof(int) + 16;
    uint4* entries = (uint4*)ws;                     // NBLK * ECAP * 16 B = 1 MiB

    fused_front<<<64 + RANKB + 1, 256, 0, stream>>>(boxes, scores, loc, deltas, stride,
                                                    pred_out, maxc, sidx, counts);
    edge_kernel<<<NTRI, 64, 0, stream>>>(boxes, cls, maxc, sidx, counts, entries);
    scan_kernel<<<1, 64, 0, stream>>>(counts, entries, sidx, keep_out);
}